// Round 1
// baseline (421.345 us; speedup 1.0000x reference)
//
#include <hip/hip_runtime.h>

// LightplaneSplatter: splat per-ray encodings (C=16) along ray samples into a
// (1,128,128,128,16) fp32 grid with trilinear weights + OOB masking.
//
// Config (from reference):
#define NS   64          // uniform samples
#define NSI  8           // disparity samples beyond far
#define ST   (NS + NSI)  // 72 samples per ray
#define GD   128
#define GH   128
#define GW   128
#define GC   16
#define DISP_INF 1e-4f

// Mapping: each 16-lane group handles one (ray, sample); lane-in-group = channel.
// The 16 channel atomics for a corner hit 64 consecutive bytes -> coalesced.
__global__ __launch_bounds__(256) void splat_kernel(
    const float* __restrict__ dirs,   // [N,3]
    const float* __restrict__ orig,   // [N,3]
    const float* __restrict__ nearv,  // [N]
    const float* __restrict__ farv,   // [N]
    const float* __restrict__ enc,    // [N,16]
    const int*   __restrict__ gidx,   // [N]
    float* __restrict__ grid,         // [1*128*128*128,16]
    int n_rays)
{
    int gt = blockIdx.x * blockDim.x + threadIdx.x;
    int group = gt >> 4;       // sample-group id
    int c = gt & 15;           // channel
    int total_groups = n_rays * ST;
    if (group >= total_groups) return;

    int ray = group / ST;
    int s   = group - ray * ST;

    float nr = nearv[ray];
    float fr = farv[ray];

    // Sample depth t (match reference fp32 arithmetic).
    float t;
    if (s < NS) {
        float frac = ((float)s + 0.5f) * (1.0f / (float)NS);
        t = nr + (fr - nr) * frac;
    } else {
        float j    = (float)(s - NS + 1) * (1.0f / (float)NSI);
        float invf = 1.0f / fr;
        float disp = invf + (DISP_INF - invf) * j;
        t = 1.0f / disp;
    }

    float dx = dirs[ray * 3 + 0];
    float dy = dirs[ray * 3 + 1];
    float dz = dirs[ray * 3 + 2];
    float ox = orig[ray * 3 + 0];
    float oy = orig[ray * 3 + 1];
    float oz = orig[ray * 3 + 2];

    float px = ox + t * dx;
    float py = oy + t * dy;
    float pz = oz + t * dz;

    // World [-1,1] -> voxel coords, align_corners=True. sizes-1 = 127 everywhere.
    float vx = (px + 1.0f) * 0.5f * 127.0f;
    float vy = (py + 1.0f) * 0.5f * 127.0f;
    float vz = (pz + 1.0f) * 0.5f * 127.0f;

    float bx = floorf(vx), by = floorf(vy), bz = floorf(vz);
    float fx = vx - bx,    fy = vy - by,    fz = vz - bz;
    int ix = (int)bx, iy = (int)by, iz = (int)bz;

    // Early-out: any axis with BOTH corners out of bounds -> zero contribution.
    if (ix < -1 || ix > GW - 1 ||
        iy < -1 || iy > GH - 1 ||
        iz < -1 || iz > GD - 1) return;

    float ev = enc[ray * GC + c];
    int g = gidx[ray];

    #pragma unroll
    for (int corner = 0; corner < 8; ++corner) {
        int cx = corner & 1;
        int cy = (corner >> 1) & 1;
        int cz = (corner >> 2) & 1;
        int jx = ix + cx, jy = iy + cy, jz = iz + cz;
        if (jx < 0 || jx >= GW || jy < 0 || jy >= GH || jz < 0 || jz >= GD)
            continue;  // MASK_OOB: masked weight is 0 -> skip
        float wx = cx ? fx : 1.0f - fx;
        float wy = cy ? fy : 1.0f - fy;
        float wz = cz ? fz : 1.0f - fz;
        float w = wx * wy * wz;
        int flat = (((g * GD + jz) * GH + jy) * GW + jx) * GC + c;
        unsafeAtomicAdd(&grid[flat], w * ev);
    }
}

extern "C" void kernel_launch(void* const* d_in, const int* in_sizes, int n_in,
                              void* d_out, int out_size, void* d_ws, size_t ws_size,
                              hipStream_t stream) {
    const float* dirs  = (const float*)d_in[0];
    const float* orig  = (const float*)d_in[1];
    const float* nearv = (const float*)d_in[2];
    const float* farv  = (const float*)d_in[3];
    const float* enc   = (const float*)d_in[4];
    const int*   gidx  = (const int*)d_in[5];
    float* out = (float*)d_out;

    int n_rays = in_sizes[2];  // near is [N]

    // Grid starts at zeros every call (harness poisons d_out, no re-poison).
    hipMemsetAsync(out, 0, (size_t)out_size * sizeof(float), stream);

    long long total_threads = (long long)n_rays * ST * 16;
    int block = 256;
    int blocks = (int)((total_threads + block - 1) / block);
    splat_kernel<<<blocks, block, 0, stream>>>(dirs, orig, nearv, farv, enc,
                                               gidx, out, n_rays);
}